// Round 3
// baseline (3107.656 us; speedup 1.0000x reference)
//
#include <hip/hip_runtime.h>
#include <math.h>

#define B_    2
#define T_    2048
#define C_    1024
#define H_    16
#define HD_   64
#define E_    8
#define NTOK  4096
#define CAP_  1024
#define FOURC 4096
#define EPS_  1e-6f

// ---------------- workspace layout (float offsets) ----------------
#define OFF_XR   ((size_t)0)                    // 4194304 : x' = l0*x + l1*x0
#define OFF_H    ((size_t)4194304)              // 4194304 : h = rmsnorm(x2)
#define OFF_MISC ((size_t)8388608)              // 32768   : eid/g0/slots/counts
#define OFF_A    (OFF_MISC + 32768)             // 4194304 : a = rmsnorm(x')   [dead after qkv]
#define OFF_O    (OFF_A + 4194304)              // 4194304 : attn out          [dead after c_proj]
#define OFF_Q    (OFF_O + 4194304)              // 4194304
#define OFF_K    (OFF_Q + 4194304)              // 4194304
#define OFF_V    (OFF_K + 4194304)              // 4194304
#define OFF_H1   OFF_A                          // 8*1024*4096 overlays dead a/o/q/k/v

__device__ __forceinline__ float4 ld4(const float* p) { return *(const float4*)p; }

// ---------------- fused (optional mix) + rmsnorm ----------------
// row per block; 256 threads * 4 floats = 1024
__global__ __launch_bounds__(256)
void k_norm(const float* __restrict__ in, const float* __restrict__ in2,
            const float* __restrict__ lambdas,
            float* __restrict__ rawOut, float* __restrict__ normOut) {
  const int row = blockIdx.x;
  const int t = threadIdx.x;
  const size_t base = (size_t)row * C_ + t * 4;
  float4 v = ld4(in + base);
  float4 m;
  if (in2 != nullptr) {
    const float l0 = lambdas[0], l1 = lambdas[1];
    float4 v2 = ld4(in2 + base);
    m.x = l0 * v.x + l1 * v2.x;
    m.y = l0 * v.y + l1 * v2.y;
    m.z = l0 * v.z + l1 * v2.z;
    m.w = l0 * v.w + l1 * v2.w;
  } else {
    m = v;
  }
  float ss = m.x * m.x + m.y * m.y + m.z * m.z + m.w * m.w;
  #pragma unroll
  for (int off = 32; off > 0; off >>= 1) ss += __shfl_xor(ss, off);
  __shared__ float red[4];
  if ((t & 63) == 0) red[t >> 6] = ss;
  __syncthreads();
  const float tot = red[0] + red[1] + red[2] + red[3];
  const float inv = 1.0f / sqrtf(tot * (1.0f / C_) + EPS_);
  if (rawOut != nullptr) *(float4*)(rawOut + base) = m;
  float4 nm;
  nm.x = m.x * inv; nm.y = m.y * inv; nm.z = m.z * inv; nm.w = m.w * inv;
  *(float4*)(normOut + base) = nm;
}

// ---------------- generic fp32 NT-GEMM: C[m,n] = sum_k A[m,k]*B[n,k] ----------------
// 128x128 tile, BK=16, 256 threads, 8x8 micro-tile (2x2 blocks of 4x4)
// MODE 0: qkv (scatter to q/k/v head layout), 1: c_proj (+bias+resid -> d_out),
// MODE 2: expert FFN1 (gathered rows, relu^2 -> h1), 3: expert FFN2 (+bias, *gate, += d_out)
#define BM 128
#define BN 128
#define BK 16
#define PA 132

template<int MODE>
__global__ __launch_bounds__(256, 2)
void k_gemm(const float* __restrict__ Ag, const float* __restrict__ Bg,
            float* __restrict__ Cg, int Kd, int lda, int ldb,
            const float* __restrict__ bias, const float* __restrict__ resid,
            float* __restrict__ oq, float* __restrict__ ok, float* __restrict__ ov,
            const int* __restrict__ slots, const int* __restrict__ counts,
            const float* __restrict__ gate, int e0) {
  __shared__ float As[BK * PA];
  __shared__ float Bs[BK * PA];
  __shared__ int rowidx[BM];

  const int tid = threadIdx.x;
  const int n0 = blockIdx.x * BN;
  const int m0 = blockIdx.y * BM;

  const float* Ab = Ag;
  const float* Bb = Bg;
  const float* biasb = bias;
  int e = 0;
  if (MODE == 2 || MODE == 3) {
    e = e0 + blockIdx.z;
    int Ne = counts[e]; if (Ne > CAP_) Ne = CAP_;
    if (m0 >= Ne) return;  // block-uniform
    if (MODE == 2) {
      Bb = Bg + (size_t)e * FOURC * C_;
      biasb = bias + (size_t)e * FOURC;
    } else {
      Ab = Ag + (size_t)blockIdx.z * CAP_ * FOURC;
      Bb = Bg + (size_t)e * C_ * FOURC;
      biasb = bias + (size_t)e * C_;
    }
    if (tid < BM) {
      const int m = m0 + tid;
      rowidx[tid] = (m < Ne) ? slots[e * CAP_ + m] : -1;
    }
    __syncthreads();
  }

  const int r = tid >> 2;            // 0..63
  const int f4 = (tid & 3) * 4;      // 0,4,8,12

  const float *pa0, *pa1;
  bool va0 = true, va1 = true;
  if (MODE == 2) {
    const int g0i = rowidx[r], g1i = rowidx[r + 64];
    va0 = g0i >= 0; va1 = g1i >= 0;
    pa0 = Ab + (size_t)(va0 ? g0i : 0) * lda + f4;
    pa1 = Ab + (size_t)(va1 ? g1i : 0) * lda + f4;
  } else if (MODE == 3) {
    va0 = rowidx[r] >= 0; va1 = rowidx[r + 64] >= 0;
    pa0 = Ab + (size_t)(m0 + r) * lda + f4;
    pa1 = Ab + (size_t)(m0 + r + 64) * lda + f4;
  } else {
    pa0 = Ab + (size_t)(m0 + r) * lda + f4;
    pa1 = Ab + (size_t)(m0 + r + 64) * lda + f4;
  }
  const float* pb0 = Bb + (size_t)(n0 + r) * ldb + f4;
  const float* pb1 = Bb + (size_t)(n0 + r + 64) * ldb + f4;

  const float4 z4 = make_float4(0.f, 0.f, 0.f, 0.f);
  float4 ga0, ga1, gb0, gb1;
  const int nkt = Kd >> 4;

  ga0 = va0 ? ld4(pa0) : z4;
  ga1 = va1 ? ld4(pa1) : z4;
  gb0 = ld4(pb0);
  gb1 = ld4(pb1);

  const int tx = tid & 15, ty = tid >> 4;
  float acc[8][8];
  #pragma unroll
  for (int i = 0; i < 8; i++)
    #pragma unroll
    for (int j = 0; j < 8; j++) acc[i][j] = 0.f;

  for (int kt = 0; kt < nkt; kt++) {
    __syncthreads();
    #pragma unroll
    for (int l = 0; l < 4; l++) {
      As[(f4 + l) * PA + r]      = (&ga0.x)[l];
      As[(f4 + l) * PA + r + 64] = (&ga1.x)[l];
      Bs[(f4 + l) * PA + r]      = (&gb0.x)[l];
      Bs[(f4 + l) * PA + r + 64] = (&gb1.x)[l];
    }
    __syncthreads();
    if (kt + 1 < nkt) {
      const int k0 = (kt + 1) * BK;
      ga0 = va0 ? ld4(pa0 + k0) : z4;
      ga1 = va1 ? ld4(pa1 + k0) : z4;
      gb0 = ld4(pb0 + k0);
      gb1 = ld4(pb1 + k0);
    }
    #pragma unroll
    for (int kk = 0; kk < BK; kk++) {
      float4 a0 = *(float4*)&As[kk * PA + ty * 4];
      float4 a1 = *(float4*)&As[kk * PA + ty * 4 + 64];
      float4 b0 = *(float4*)&Bs[kk * PA + tx * 4];
      float4 b1 = *(float4*)&Bs[kk * PA + tx * 4 + 64];
      float av[8] = {a0.x, a0.y, a0.z, a0.w, a1.x, a1.y, a1.z, a1.w};
      float bv[8] = {b0.x, b0.y, b0.z, b0.w, b1.x, b1.y, b1.z, b1.w};
      #pragma unroll
      for (int i = 0; i < 8; i++)
        #pragma unroll
        for (int j = 0; j < 8; j++) acc[i][j] += av[i] * bv[j];
    }
  }

  // epilogue
  #pragma unroll
  for (int ih = 0; ih < 2; ih++) {
    #pragma unroll
    for (int ii = 0; ii < 4; ii++) {
      const int i = ih * 4 + ii;
      const int mloc = ty * 4 + ii + ih * 64;
      const int m = m0 + mloc;
      #pragma unroll
      for (int jh = 0; jh < 2; jh++) {
        const int n = n0 + tx * 4 + jh * 64;
        float4 vv = make_float4(acc[i][jh * 4 + 0], acc[i][jh * 4 + 1],
                                acc[i][jh * 4 + 2], acc[i][jh * 4 + 3]);
        if (MODE == 0) {
          const int kap = n >> 10;
          const int hh = (n >> 6) & 15;
          const int d = n & 63;
          const int bq = m >> 11, tq = m & 2047;
          float* dst = (kap == 0) ? oq : ((kap == 1) ? ok : ov);
          *(float4*)(dst + ((size_t)((bq * 16 + hh) * 2048 + tq)) * 64 + d) = vv;
        } else if (MODE == 1) {
          float4 bb = ld4(biasb + n);
          float4 rr = ld4(resid + (size_t)m * C_ + n);
          vv.x += bb.x + rr.x; vv.y += bb.y + rr.y;
          vv.z += bb.z + rr.z; vv.w += bb.w + rr.w;
          *(float4*)(Cg + (size_t)m * C_ + n) = vv;
        } else if (MODE == 2) {
          if (rowidx[mloc] >= 0) {
            float4 bb = ld4(biasb + n);
            float t0;
            t0 = fmaxf(vv.x + bb.x, 0.f); vv.x = t0 * t0;
            t0 = fmaxf(vv.y + bb.y, 0.f); vv.y = t0 * t0;
            t0 = fmaxf(vv.z + bb.z, 0.f); vv.z = t0 * t0;
            t0 = fmaxf(vv.w + bb.w, 0.f); vv.w = t0 * t0;
            *(float4*)(Cg + (size_t)blockIdx.z * CAP_ * FOURC + (size_t)m * FOURC + n) = vv;
          }
        } else {  // MODE 3
          const int token = rowidx[mloc];
          if (token >= 0) {
            float4 bb = ld4(biasb + n);
            const float gg = gate[token];
            float* dp = Cg + (size_t)token * C_ + n;
            float4 cur = *(float4*)dp;
            cur.x += (vv.x + bb.x) * gg; cur.y += (vv.y + bb.y) * gg;
            cur.z += (vv.z + bb.z) * gg; cur.w += (vv.w + bb.w) * gg;
            *(float4*)dp = cur;
          }
        }
      }
    }
  }
}

// ---------------- q/k rmsnorm + rotary (one wave per 64-dim row) ----------------
__global__ __launch_bounds__(256)
void k_qkrot(float* __restrict__ qb, float* __restrict__ kb) {
  const int w = threadIdx.x >> 6, lane = threadIdx.x & 63;
  const int row = blockIdx.x * 4 + w;            // 0..65535 = bh*2048 + t
  float* buf = (blockIdx.y == 0) ? qb : kb;
  const int t = row & 2047;
  float val = buf[(size_t)row * 64 + lane];
  float ss = val * val;
  #pragma unroll
  for (int off = 32; off > 0; off >>= 1) ss += __shfl_xor(ss, off);
  const float nrm = val / sqrtf(ss * (1.0f / 64.0f) + EPS_);
  const int i = lane & 31;
  float c, s;
  if (i < 16) {
    const float y = (float)i * (1.0f / 15.0f);     // linspace(0,1,16) = iota*step
    const float inv = exp2f(-10.0f * y);           // (1/1024)^y = 2^(-10y), exact base
    const float ang = (float)t * inv;
    c = cosf(ang); s = sinf(ang);
  } else { c = 1.0f; s = 0.0f; }
  const float partner = __shfl_xor(nrm, 32);
  const float out = (lane < 32) ? (nrm * c + partner * s) : (partner * (-s) + nrm * c);
  buf[(size_t)row * 64 + lane] = out;
}

// ---------------- causal flash attention, fp32 ----------------
// block: 256 thr = 4 waves; each wave owns 4 query rows; 64-key LDS tiles.
// K and V^T stored XOR-swizzled so ds_read_b128 is ~conflict-free.
__global__ __launch_bounds__(256)
void k_attn(const float* __restrict__ q, const float* __restrict__ k,
            const float* __restrict__ v, float* __restrict__ o) {
  const int bh = blockIdx.y;     // 0..31
  const int rg = blockIdx.x;     // 0..127 (16 rows each; never straddles 64-boundary)
  const int tid = threadIdx.x;
  const int w = tid >> 6, lane = tid & 63;
  __shared__ float qs[16 * 64];
  __shared__ float Ks[64 * 64];   // [j][d^( (j&7)<<3 )]
  __shared__ float Vt[64 * 64];   // [d][j^( (d&7)<<3 )]
  __shared__ float ps[16 * 64];
  const size_t base = (size_t)bh * T_ * HD_;

  {  // stage q, pre-scaled by 1/sqrt(HD)
    const int rr = tid >> 4;
    const int d0 = (tid & 15) * 4;
    float4 qv = ld4(q + base + (size_t)(rg * 16 + rr) * 64 + d0);
    qv.x *= 0.125f; qv.y *= 0.125f; qv.z *= 0.125f; qv.w *= 0.125f;
    *(float4*)&qs[rr * 64 + d0] = qv;
  }

  float oacc[4] = {0.f, 0.f, 0.f, 0.f};
  float mrow[4] = {-INFINITY, -INFINITY, -INFINITY, -INFINITY};
  float lrow[4] = {0.f, 0.f, 0.f, 0.f};
  const int trow0 = rg * 16 + w * 4;
  const int ktmax = (rg * 16 + 15) >> 6;

  for (int kt = 0; kt <= ktmax; kt++) {
    const int j0 = kt * 64;
    // stage K / V^T tiles: 64 rows x 64 dims = 4096 floats each.
    // 256 threads x 4 float4 loads: each thread covers rows {0,16,32,48}+ (tid>>4).
    #pragma unroll
    for (int r4 = 0; r4 < 4; r4++) {
      const int jj = r4 * 16 + (tid >> 4);
      const int d0 = (tid & 15) * 4;
      float4 kv = ld4(k + base + (size_t)(j0 + jj) * 64 + d0);
      *(float4*)&Ks[jj * 64 + (d0 ^ ((jj & 7) << 3))] = kv;
      float4 vv = ld4(v + base + (size_t)(j0 + jj) * 64 + d0);
      Vt[(d0 + 0) * 64 + (jj ^ (((d0 + 0) & 7) << 3))] = vv.x;
      Vt[(d0 + 1) * 64 + (jj ^ (((d0 + 1) & 7) << 3))] = vv.y;
      Vt[(d0 + 2) * 64 + (jj ^ (((d0 + 2) & 7) << 3))] = vv.z;
      Vt[(d0 + 3) * 64 + (jj ^ (((d0 + 3) & 7) << 3))] = vv.w;
    }
    __syncthreads();

    // scores: lane = key j
    float s[4] = {0.f, 0.f, 0.f, 0.f};
    const int xoK = (lane & 7) << 3;
    #pragma unroll
    for (int d4 = 0; d4 < 16; d4++) {
      float4 k4 = *(float4*)&Ks[lane * 64 + ((d4 * 4) ^ xoK)];
      #pragma unroll
      for (int rr = 0; rr < 4; rr++) {
        float4 q4 = *(float4*)&qs[(w * 4 + rr) * 64 + d4 * 4];
        s[rr] += k4.x * q4.x + k4.y * q4.y + k4.z * q4.z + k4.w * q4.w;
      }
    }
    // online softmax per row
    #pragma unroll
    for (int rr = 0; rr < 4; rr++) {
      const int trow = trow0 + rr;
      float sv = (j0 + lane <= trow) ? s[rr] : -INFINITY;
      float mt = sv;
      #pragma unroll
      for (int off = 32; off > 0; off >>= 1) mt = fmaxf(mt, __shfl_xor(mt, off));
      const float mnew = fmaxf(mrow[rr], mt);
      const float alpha = expf(mrow[rr] - mnew);
      const float p = expf(sv - mnew);
      float psum = p;
      #pragma unroll
      for (int off = 32; off > 0; off >>= 1) psum += __shfl_xor(psum, off);
      lrow[rr] = lrow[rr] * alpha + psum;
      mrow[rr] = mnew;
      oacc[rr] *= alpha;
      ps[(w * 4 + rr) * 64 + lane] = p;
    }
    // PV: lane = dim d
    const int xoV = (lane & 7) << 3;
    #pragma unroll
    for (int j4 = 0; j4 < 16; j4++) {
      float4 v4 = *(float4*)&Vt[lane * 64 + ((j4 * 4) ^ xoV)];
      #pragma unroll
      for (int rr = 0; rr < 4; rr++) {
        float4 p4 = *(float4*)&ps[(w * 4 + rr) * 64 + j4 * 4];
        oacc[rr] += p4.x * v4.x + p4.y * v4.y + p4.z * v4.z + p4.w * v4.w;
      }
    }
    __syncthreads();
  }

  const int b = bh >> 4, hh = bh & 15;
  #pragma unroll
  for (int rr = 0; rr < 4; rr++) {
    const int trow = trow0 + rr;
    o[((size_t)(b * 2048 + trow)) * 1024 + hh * 64 + lane] = oacc[rr] / lrow[rr];
  }
}

// ---------------- router: logits, noisy top-2, gate ----------------
__global__ __launch_bounds__(256)
void k_router(const float* __restrict__ h, const float* __restrict__ rw,
              const float* __restrict__ rb, const float* __restrict__ nw,
              const float* __restrict__ nb, const float* __restrict__ noise,
              int* __restrict__ eid, float* __restrict__ gate0) {
  const int m = blockIdx.x;
  const int t = threadIdx.x;
  const float4 hv = ld4(h + (size_t)m * C_ + t * 4);
  float pl[E_], pn[E_];
  #pragma unroll
  for (int e2 = 0; e2 < E_; e2++) {
    float4 wv = ld4(rw + (size_t)e2 * C_ + t * 4);
    pl[e2] = hv.x * wv.x + hv.y * wv.y + hv.z * wv.z + hv.w * wv.w;
    float4 nv = ld4(nw + (size_t)e2 * C_ + t * 4);
    pn[e2] = hv.x * nv.x + hv.y * nv.y + hv.z * nv.z + hv.w * nv.w;
  }
  __shared__ float red[16][4];
  const int w = t >> 6, lane = t & 63;
  #pragma unroll
  for (int idx = 0; idx < 16; idx++) {
    float val = (idx < 8) ? pl[idx] : pn[idx - 8];
    #pragma unroll
    for (int off = 32; off > 0; off >>= 1) val += __shfl_xor(val, off);
    if (lane == 0) red[idx][w] = val;
  }
  __syncthreads();
  if (t == 0) {
    float noisy[E_];
    #pragma unroll
    for (int e2 = 0; e2 < E_; e2++) {
      const float lg = red[e2][0] + red[e2][1] + red[e2][2] + red[e2][3] + rb[e2];
      const float nl = red[8 + e2][0] + red[8 + e2][1] + red[8 + e2][2] + red[8 + e2][3] + nb[e2];
      const float sp = fmaxf(nl, 0.f) + log1pf(expf(-fabsf(nl)));  // softplus
      noisy[e2] = lg + noise[m * E_ + e2] * sp;
    }
    int i0 = 0; float v0 = noisy[0];
    #pragma unroll
    for (int e2 = 1; e2 < E_; e2++)
      if (noisy[e2] > v0) { v0 = noisy[e2]; i0 = e2; }
    float v1 = -INFINITY;
    #pragma unroll
    for (int e2 = 0; e2 < E_; e2++)
      if (e2 != i0 && noisy[e2] > v1) { v1 = noisy[e2]; }
    eid[m] = i0;
    gate0[m] = 1.0f / (1.0f + expf(v1 - v0));  // softmax([v0,v1])[0]
  }
}

// ---------------- ordered per-expert compaction (1 block) ----------------
__global__ __launch_bounds__(256)
void k_assign(const int* __restrict__ eid, int* __restrict__ slots,
              int* __restrict__ counts) {
  const int t = threadIdx.x;
  int myeid[16];
  #pragma unroll
  for (int i = 0; i < 16; i++) myeid[i] = eid[t * 16 + i];
  int cnt[E_];
  #pragma unroll
  for (int e2 = 0; e2 < E_; e2++) {
    int c = 0;
    #pragma unroll
    for (int i = 0; i < 16; i++) c += (myeid[i] == e2) ? 1 : 0;
    cnt[e2] = c;
  }
  __shared__ int sc[256];
  #pragma unroll
  for (int e2 = 0; e2 < E_; e2++) {
    sc[t] = cnt[e2];
    __syncthreads();
    for (int off = 1; off < 256; off <<= 1) {
      int xv = (t >= off) ? sc[t - off] : 0;
      __syncthreads();
      sc[t] += xv;
      __syncthreads();
    }
    int rank = sc[t] - cnt[e2];
    if (t == 255) counts[e2] = sc[255];
    #pragma unroll
    for (int i = 0; i < 16; i++) {
      if (myeid[i] == e2) {
        if (rank < CAP_) slots[e2 * CAP_ + rank] = t * 16 + i;
        rank++;
      }
    }
    __syncthreads();
  }
}

// ---------------- launcher ----------------
extern "C" void kernel_launch(void* const* d_in, const int* in_sizes, int n_in,
                              void* d_out, int out_size, void* d_ws, size_t ws_size,
                              hipStream_t stream) {
  const float* x        = (const float*)d_in[0];
  const float* x0       = (const float*)d_in[1];
  const float* noise    = (const float*)d_in[2];
  const float* lambdas  = (const float*)d_in[3];
  // d_in[4] = lamb: (1-lamb)*v + lamb*v == v exactly -> unused
  const float* qkv_w    = (const float*)d_in[5];
  const float* c_proj_w = (const float*)d_in[6];
  const float* c_proj_b = (const float*)d_in[7];
  const float* router_w = (const float*)d_in[8];
  const float* router_b = (const float*)d_in[9];
  const float* noise_w  = (const float*)d_in[10];
  const float* noise_b  = (const float*)d_in[11];
  const float* ew1      = (const float*)d_in[12];
  const float* eb1      = (const float*)d_in[13];
  const float* ew2      = (const float*)d_in[14];
  const float* eb2      = (const float*)d_in[15];
  float* out = (float*)d_out;
  float* ws  = (float*)d_ws;

  float* xr  = ws + OFF_XR;
  float* h   = ws + OFF_H;
  int*   eid    = (int*)(ws + OFF_MISC);
  float* gate0  = ws + OFF_MISC + 4096;
  int*   slots  = (int*)(ws + OFF_MISC + 8192);
  int*   counts = (int*)(ws + OFF_MISC + 16384);
  float* a   = ws + OFF_A;
  float* ob  = ws + OFF_O;
  float* qb  = ws + OFF_Q;
  float* kb  = ws + OFF_K;
  float* vb  = ws + OFF_V;
  float* h1  = ws + OFF_H1;  // overlays a/o/q/k/v (dead by expert phase)

  // 1) x' = l0*x + l1*x0 ; a = rmsnorm(x')
  k_norm<<<NTOK, 256, 0, stream>>>(x, x0, lambdas, xr, a);
  // 2) qkv = a @ qkv_w^T, scattered into head layout
  k_gemm<0><<<dim3(24, 32), 256, 0, stream>>>(a, qkv_w, nullptr, 1024, 1024, 1024,
      nullptr, nullptr, qb, kb, vb, nullptr, nullptr, nullptr, 0);
  // 3) per-head rmsnorm + rotary on q,k
  k_qkrot<<<dim3(16384, 2), 256, 0, stream>>>(qb, kb);
  // 4) causal attention
  k_attn<<<dim3(T_ / 16, B_ * H_), 256, 0, stream>>>(qb, kb, vb, ob);
  // 5) x2 = x' + o @ c_proj_w^T + b  -> d_out
  k_gemm<1><<<dim3(8, 32), 256, 0, stream>>>(ob, c_proj_w, out, 1024, 1024, 1024,
      c_proj_b, xr, nullptr, nullptr, nullptr, nullptr, nullptr, nullptr, 0);
  // 6) h = rmsnorm(x2)
  k_norm<<<NTOK, 256, 0, stream>>>(out, nullptr, nullptr, nullptr, h);
  // 7) router decisions
  k_router<<<NTOK, 256, 0, stream>>>(h, router_w, router_b, noise_w, noise_b,
                                     noise, eid, gate0);
  // 8) ordered compaction into per-expert slot lists
  k_assign<<<1, 256, 0, stream>>>(eid, slots, counts);
  // 9/10) expert FFNs (chunked by available workspace for h1)
  const size_t ws_floats = ws_size / 4;
  long avail = (long)ws_floats - (long)OFF_A;
  int chunk = (int)(avail / ((long)CAP_ * FOURC));
  if (chunk < 1) chunk = 1;
  if (chunk > E_) chunk = E_;
  for (int eb = 0; eb < E_; eb += chunk) {
    const int ce = (E_ - eb < chunk) ? (E_ - eb) : chunk;
    k_gemm<2><<<dim3(32, 8, ce), 256, 0, stream>>>(h, ew1, h1, 1024, 1024, 1024,
        eb1, nullptr, nullptr, nullptr, nullptr, slots, counts, nullptr, eb);
    k_gemm<3><<<dim3(8, 8, ce), 256, 0, stream>>>(h1, ew2, out, 4096, 4096, 4096,
        eb2, nullptr, nullptr, nullptr, nullptr, slots, counts, gate0, eb);
  }
}

// Round 4
// 2004.344 us; speedup vs baseline: 1.5505x; 1.5505x over previous
//
#include <hip/hip_runtime.h>
#include <math.h>

#define B_    2
#define T_    2048
#define C_    1024
#define H_    16
#define HD_   64
#define E_    8
#define NTOK  4096
#define CAP_  1024
#define FOURC 4096
#define EPS_  1e-6f
#define QBLK  32

typedef __attribute__((ext_vector_type(8))) short bf16x8;
typedef __attribute__((ext_vector_type(4))) float f32x4;

// ---------------- workspace layout (float offsets) ----------------
#define OFF_XR   ((size_t)0)                    // 4194304 : x' = l0*x + l1*x0
#define OFF_H    ((size_t)4194304)              // 4194304 : h = rmsnorm(x2)
#define OFF_MISC ((size_t)8388608)              // 32768   : eid/g0/slots/counts
#define OFF_A    (OFF_MISC + 32768)             // attention scratch, dead by expert phase
#define OFF_O    (OFF_A + 4194304)
#define OFF_Q    (OFF_O + 4194304)
#define OFF_K    (OFF_Q + 4194304)
#define OFF_V    (OFF_K + 4194304)
// expert phase overlays OFF_A.. : h_bf16 (2M floats) + chunk{ew1b,ew2b,h1b}

__device__ __forceinline__ float4 ld4(const float* p) { return *(const float4*)p; }

__device__ __forceinline__ unsigned short f2b(float x) {  // fp32 -> bf16 RNE
  unsigned int u = __float_as_uint(x);
  u = (u + 0x7FFFu + ((u >> 16) & 1u)) >> 16;
  return (unsigned short)u;
}

// ---------------- fused (optional mix) + rmsnorm ----------------
__global__ __launch_bounds__(256)
void k_norm(const float* __restrict__ in, const float* __restrict__ in2,
            const float* __restrict__ lambdas,
            float* __restrict__ rawOut, float* __restrict__ normOut) {
  const int row = blockIdx.x;
  const int t = threadIdx.x;
  const size_t base = (size_t)row * C_ + t * 4;
  float4 v = ld4(in + base);
  float4 m;
  if (in2 != nullptr) {
    const float l0 = lambdas[0], l1 = lambdas[1];
    float4 v2 = ld4(in2 + base);
    m.x = l0 * v.x + l1 * v2.x;
    m.y = l0 * v.y + l1 * v2.y;
    m.z = l0 * v.z + l1 * v2.z;
    m.w = l0 * v.w + l1 * v2.w;
  } else {
    m = v;
  }
  float ss = m.x * m.x + m.y * m.y + m.z * m.z + m.w * m.w;
  #pragma unroll
  for (int off = 32; off > 0; off >>= 1) ss += __shfl_xor(ss, off);
  __shared__ float red[4];
  if ((t & 63) == 0) red[t >> 6] = ss;
  __syncthreads();
  const float tot = red[0] + red[1] + red[2] + red[3];
  const float inv = 1.0f / sqrtf(tot * (1.0f / C_) + EPS_);
  if (rawOut != nullptr) *(float4*)(rawOut + base) = m;
  float4 nm;
  nm.x = m.x * inv; nm.y = m.y * inv; nm.z = m.z * inv; nm.w = m.w * inv;
  *(float4*)(normOut + base) = nm;
}

// ---------------- fp32 NT-GEMM (qkv / c_proj only) ----------------
#define BM 128
#define BN 128
#define BK 16
#define PA 132

template<int MODE>   // 0: qkv scatter, 1: c_proj + bias + resid
__global__ __launch_bounds__(256, 2)
void k_gemm(const float* __restrict__ Ag, const float* __restrict__ Bg,
            float* __restrict__ Cg, int Kd, int lda, int ldb,
            const float* __restrict__ bias, const float* __restrict__ resid,
            float* __restrict__ oq, float* __restrict__ ok, float* __restrict__ ov) {
  __shared__ float As[BK * PA];
  __shared__ float Bs[BK * PA];

  const int tid = threadIdx.x;
  const int n0 = blockIdx.x * BN;
  const int m0 = blockIdx.y * BM;

  const int r = tid >> 2;            // 0..63
  const int f4 = (tid & 3) * 4;      // 0,4,8,12

  const float* pa0 = Ag + (size_t)(m0 + r) * lda + f4;
  const float* pa1 = Ag + (size_t)(m0 + r + 64) * lda + f4;
  const float* pb0 = Bg + (size_t)(n0 + r) * ldb + f4;
  const float* pb1 = Bg + (size_t)(n0 + r + 64) * ldb + f4;

  float4 ga0, ga1, gb0, gb1;
  const int nkt = Kd >> 4;

  ga0 = ld4(pa0); ga1 = ld4(pa1); gb0 = ld4(pb0); gb1 = ld4(pb1);

  const int tx = tid & 15, ty = tid >> 4;
  float acc[8][8];
  #pragma unroll
  for (int i = 0; i < 8; i++)
    #pragma unroll
    for (int j = 0; j < 8; j++) acc[i][j] = 0.f;

  for (int kt = 0; kt < nkt; kt++) {
    __syncthreads();
    #pragma unroll
    for (int l = 0; l < 4; l++) {
      As[(f4 + l) * PA + r]      = (&ga0.x)[l];
      As[(f4 + l) * PA + r + 64] = (&ga1.x)[l];
      Bs[(f4 + l) * PA + r]      = (&gb0.x)[l];
      Bs[(f4 + l) * PA + r + 64] = (&gb1.x)[l];
    }
    __syncthreads();
    if (kt + 1 < nkt) {
      const int k0 = (kt + 1) * BK;
      ga0 = ld4(pa0 + k0); ga1 = ld4(pa1 + k0);
      gb0 = ld4(pb0 + k0); gb1 = ld4(pb1 + k0);
    }
    #pragma unroll
    for (int kk = 0; kk < BK; kk++) {
      float4 a0 = *(float4*)&As[kk * PA + ty * 4];
      float4 a1 = *(float4*)&As[kk * PA + ty * 4 + 64];
      float4 b0 = *(float4*)&Bs[kk * PA + tx * 4];
      float4 b1 = *(float4*)&Bs[kk * PA + tx * 4 + 64];
      float av[8] = {a0.x, a0.y, a0.z, a0.w, a1.x, a1.y, a1.z, a1.w};
      float bv[8] = {b0.x, b0.y, b0.z, b0.w, b1.x, b1.y, b1.z, b1.w};
      #pragma unroll
      for (int i = 0; i < 8; i++)
        #pragma unroll
        for (int j = 0; j < 8; j++) acc[i][j] += av[i] * bv[j];
    }
  }

  #pragma unroll
  for (int ih = 0; ih < 2; ih++) {
    #pragma unroll
    for (int ii = 0; ii < 4; ii++) {
      const int i = ih * 4 + ii;
      const int m = m0 + ty * 4 + ii + ih * 64;
      #pragma unroll
      for (int jh = 0; jh < 2; jh++) {
        const int n = n0 + tx * 4 + jh * 64;
        float4 vv = make_float4(acc[i][jh * 4 + 0], acc[i][jh * 4 + 1],
                                acc[i][jh * 4 + 2], acc[i][jh * 4 + 3]);
        if (MODE == 0) {
          const int kap = n >> 10;
          const int hh = (n >> 6) & 15;
          const int d = n & 63;
          const int bq = m >> 11, tq = m & 2047;
          float* dst = (kap == 0) ? oq : ((kap == 1) ? ok : ov);
          *(float4*)(dst + ((size_t)((bq * 16 + hh) * 2048 + tq)) * 64 + d) = vv;
        } else {
          float4 bb = ld4(bias + n);
          float4 rr = ld4(resid + (size_t)m * C_ + n);
          vv.x += bb.x + rr.x; vv.y += bb.y + rr.y;
          vv.z += bb.z + rr.z; vv.w += bb.w + rr.w;
          *(float4*)(Cg + (size_t)m * C_ + n) = vv;
        }
      }
    }
  }
}

// ---------------- q/k rmsnorm + rotary ----------------
__global__ __launch_bounds__(256)
void k_qkrot(float* __restrict__ qb, float* __restrict__ kb) {
  const int w = threadIdx.x >> 6, lane = threadIdx.x & 63;
  const int row = blockIdx.x * 4 + w;
  float* buf = (blockIdx.y == 0) ? qb : kb;
  const int t = row & 2047;
  float val = buf[(size_t)row * 64 + lane];
  float ss = val * val;
  #pragma unroll
  for (int off = 32; off > 0; off >>= 1) ss += __shfl_xor(ss, off);
  const float nrm = val / sqrtf(ss * (1.0f / 64.0f) + EPS_);
  const int i = lane & 31;
  float c, s;
  if (i < 16) {
    const float y = (float)i * (1.0f / 15.0f);
    const float inv = exp2f(-10.0f * y);           // (1/1024)^y
    const float ang = (float)t * inv;
    c = cosf(ang); s = sinf(ang);
  } else { c = 1.0f; s = 0.0f; }
  const float partner = __shfl_xor(nrm, 32);
  const float out = (lane < 32) ? (nrm * c + partner * s) : (partner * (-s) + nrm * c);
  buf[(size_t)row * 64 + lane] = out;
}

// ---------------- causal flash attention, fp32, fixed-max softmax ----------------
// 512 thr = 8 waves; wave owns 4 q-rows; 64-key LDS tiles.
// |s| <= 8 exactly (rmsnorm'd q,k, rotary orthogonal) -> p = exp(s-8), no max
// tracking, no rescale; per-lane partial sums reduced once at the end.
// fp32 swizzle: 4-float blocks, blk ^= (row&7) -> 8 distinct 16B bank slots.
__global__ __launch_bounds__(512, 4)
void k_attn(const float* __restrict__ q, const float* __restrict__ k,
            const float* __restrict__ v, float* __restrict__ o) {
  const int bh = blockIdx.y;     // 0..31
  const int rg = blockIdx.x;     // 0..63
  const int tid = threadIdx.x;
  const int w = tid >> 6, lane = tid & 63;
  __shared__ float qs[QBLK * 64];
  __shared__ float Ks[64 * 64];   // [j][ (blk^(j&7))*4 + sub ]
  __shared__ float Vt[64 * 64];   // [d][ (jblk^(d&7))*4 + jsub ]
  __shared__ float ps[QBLK * 64];
  const size_t base = (size_t)bh * T_ * HD_;

  {  // stage q, pre-scaled by 1/sqrt(HD): 32 rows x 64 = 512 float4
    const int rr = tid >> 4;          // 0..31
    const int d0 = (tid & 15) * 4;
    float4 qv = ld4(q + base + (size_t)(rg * QBLK + rr) * 64 + d0);
    qv.x *= 0.125f; qv.y *= 0.125f; qv.z *= 0.125f; qv.w *= 0.125f;
    *(float4*)&qs[rr * 64 + d0] = qv;
  }

  float oacc[4] = {0.f, 0.f, 0.f, 0.f};
  float lsum[4] = {0.f, 0.f, 0.f, 0.f};
  const int trow0 = rg * QBLK + w * 4;
  const int ktmax = (rg * QBLK + QBLK - 1) >> 6;

  for (int kt = 0; kt <= ktmax; kt++) {
    const int j0 = kt * 64;
    __syncthreads();   // prior tile fully consumed
    {  // stage K: rows jj, cols d0 (coalesced 4x256B per wave)
      const int d0 = (tid & 15) * 4;
      #pragma unroll
      for (int r2 = 0; r2 < 2; r2++) {
        const int jj = r2 * 32 + (tid >> 4);
        float4 kv = ld4(k + base + (size_t)(j0 + jj) * 64 + d0);
        *(float4*)&Ks[jj * 64 + ((((d0 >> 2) ^ (jj & 7)) << 2))] = kv;
      }
      // stage V^T: j from (tid&15)+(tid>>8)*16, d from (tid>>4)&15
      const int d0v = ((tid >> 4) & 15) * 4;
      #pragma unroll
      for (int r2 = 0; r2 < 2; r2++) {
        const int jj = r2 * 32 + ((tid >> 8) << 4) + (tid & 15);
        float4 vv = ld4(v + base + (size_t)(j0 + jj) * 64 + d0v);
        #pragma unroll
        for (int i = 0; i < 4; i++) {
          const int d = d0v + i;
          Vt[d * 64 + ((((jj >> 2) ^ (d & 7)) << 2) | (jj & 3))] = (&vv.x)[i];
        }
      }
    }
    __syncthreads();

    // scores: lane = key j
    float s[4] = {0.f, 0.f, 0.f, 0.f};
    #pragma unroll
    for (int d4 = 0; d4 < 16; d4++) {
      float4 k4 = *(float4*)&Ks[lane * 64 + (((d4 ^ (lane & 7)) << 2))];
      #pragma unroll
      for (int rr = 0; rr < 4; rr++) {
        float4 q4 = *(float4*)&qs[(w * 4 + rr) * 64 + d4 * 4];
        s[rr] += k4.x * q4.x + k4.y * q4.y + k4.z * q4.z + k4.w * q4.w;
      }
    }
    // fixed-max softmax partials (no cross-lane reduction per tile)
    #pragma unroll
    for (int rr = 0; rr < 4; rr++) {
      const float p = (j0 + lane <= trow0 + rr) ? expf(s[rr] - 8.0f) : 0.f;
      lsum[rr] += p;
      ps[(w * 4 + rr) * 64 + lane] = p;   // intra-wave only: no barrier needed
    }
    // PV: lane = dim d
    #pragma unroll
    for (int j4 = 0; j4 < 16; j4++) {
      float4 v4 = *(float4*)&Vt[lane * 64 + (((j4 ^ (lane & 7)) << 2))];
      #pragma unroll
      for (int rr = 0; rr < 4; rr++) {
        float4 p4 = *(float4*)&ps[(w * 4 + rr) * 64 + j4 * 4];
        oacc[rr] += p4.x * v4.x + p4.y * v4.y + p4.z * v4.z + p4.w * v4.w;
      }
    }
  }

  const int b = bh >> 4, hh = bh & 15;
  #pragma unroll
  for (int rr = 0; rr < 4; rr++) {
    float tsum = lsum[rr];
    #pragma unroll
    for (int off = 32; off > 0; off >>= 1) tsum += __shfl_xor(tsum, off);
    const int trow = trow0 + rr;
    o[((size_t)(b * 2048 + trow)) * 1024 + hh * 64 + lane] = oacc[rr] / tsum;
  }
}

// ---------------- router ----------------
__global__ __launch_bounds__(256)
void k_router(const float* __restrict__ h, const float* __restrict__ rw,
              const float* __restrict__ rb, const float* __restrict__ nw,
              const float* __restrict__ nb, const float* __restrict__ noise,
              int* __restrict__ eid, float* __restrict__ gate0) {
  const int m = blockIdx.x;
  const int t = threadIdx.x;
  const float4 hv = ld4(h + (size_t)m * C_ + t * 4);
  float pl[E_], pn[E_];
  #pragma unroll
  for (int e2 = 0; e2 < E_; e2++) {
    float4 wv = ld4(rw + (size_t)e2 * C_ + t * 4);
    pl[e2] = hv.x * wv.x + hv.y * wv.y + hv.z * wv.z + hv.w * wv.w;
    float4 nv = ld4(nw + (size_t)e2 * C_ + t * 4);
    pn[e2] = hv.x * nv.x + hv.y * nv.y + hv.z * nv.z + hv.w * nv.w;
  }
  __shared__ float red[16][4];
  const int w = t >> 6, lane = t & 63;
  #pragma unroll
  for (int idx = 0; idx < 16; idx++) {
    float val = (idx < 8) ? pl[idx] : pn[idx - 8];
    #pragma unroll
    for (int off = 32; off > 0; off >>= 1) val += __shfl_xor(val, off);
    if (lane == 0) red[idx][w] = val;
  }
  __syncthreads();
  if (t == 0) {
    float noisy[E_];
    #pragma unroll
    for (int e2 = 0; e2 < E_; e2++) {
      const float lg = red[e2][0] + red[e2][1] + red[e2][2] + red[e2][3] + rb[e2];
      const float nl = red[8 + e2][0] + red[8 + e2][1] + red[8 + e2][2] + red[8 + e2][3] + nb[e2];
      const float sp = fmaxf(nl, 0.f) + log1pf(expf(-fabsf(nl)));
      noisy[e2] = lg + noise[m * E_ + e2] * sp;
    }
    int i0 = 0; float v0 = noisy[0];
    #pragma unroll
    for (int e2 = 1; e2 < E_; e2++)
      if (noisy[e2] > v0) { v0 = noisy[e2]; i0 = e2; }
    float v1 = -INFINITY;
    #pragma unroll
    for (int e2 = 0; e2 < E_; e2++)
      if (e2 != i0 && noisy[e2] > v1) { v1 = noisy[e2]; }
    eid[m] = i0;
    gate0[m] = 1.0f / (1.0f + expf(v1 - v0));
  }
}

// ---------------- ordered per-expert compaction ----------------
__global__ __launch_bounds__(256)
void k_assign(const int* __restrict__ eid, int* __restrict__ slots,
              int* __restrict__ counts) {
  const int t = threadIdx.x;
  int myeid[16];
  #pragma unroll
  for (int i = 0; i < 16; i++) myeid[i] = eid[t * 16 + i];
  int cnt[E_];
  #pragma unroll
  for (int e2 = 0; e2 < E_; e2++) {
    int c = 0;
    #pragma unroll
    for (int i = 0; i < 16; i++) c += (myeid[i] == e2) ? 1 : 0;
    cnt[e2] = c;
  }
  __shared__ int sc[256];
  #pragma unroll
  for (int e2 = 0; e2 < E_; e2++) {
    sc[t] = cnt[e2];
    __syncthreads();
    for (int off = 1; off < 256; off <<= 1) {
      int xv = (t >= off) ? sc[t - off] : 0;
      __syncthreads();
      sc[t] += xv;
      __syncthreads();
    }
    int rank = sc[t] - cnt[e2];
    if (t == 255) counts[e2] = sc[255];
    #pragma unroll
    for (int i = 0; i < 16; i++) {
      if (myeid[i] == e2) {
        if (rank < CAP_) slots[e2 * CAP_ + rank] = t * 16 + i;
        rank++;
      }
    }
    __syncthreads();
  }
}

// ---------------- fp32 -> bf16 cast (grid-stride over float4) ----------------
__global__ __launch_bounds__(256)
void k_cast(const float* __restrict__ in, unsigned short* __restrict__ outp, int n4) {
  for (int i = blockIdx.x * 256 + threadIdx.x; i < n4; i += gridDim.x * 256) {
    float4 vv = ld4(in + (size_t)i * 4);
    ushort4 u;
    u.x = f2b(vv.x); u.y = f2b(vv.y); u.z = f2b(vv.z); u.w = f2b(vv.w);
    *(ushort4*)(outp + (size_t)i * 4) = u;
  }
}

// ---------------- bf16 MFMA NT-GEMM for experts ----------------
// 128x128 tile, BK=64, 4 waves (2x2 quadrants of 64x64), 16x16x32 MFMA.
// MODE 0 (FFN1): A = h_bf16 gathered via slots, epilogue relu^2 -> bf16 h1.
// MODE 1 (FFN2): A = h1 rows direct, epilogue (acc+bias)*gate += d_out.
template<int MODE>
__global__ __launch_bounds__(256, 4)
void k_mgemm(const unsigned short* __restrict__ Ab, const unsigned short* __restrict__ Bb,
             int Kd, int lda, int ldb,
             const float* __restrict__ bias,
             unsigned short* __restrict__ h1out, float* __restrict__ fout,
             const int* __restrict__ slots, const int* __restrict__ counts,
             const float* __restrict__ gate, int e0) {
  const int z = blockIdx.z, e = e0 + z;
  int Ne = counts[e]; if (Ne > CAP_) Ne = CAP_;
  const int m0 = blockIdx.y * 128, n0 = blockIdx.x * 128;
  if (m0 >= Ne) return;

  __shared__ __align__(16) unsigned short Asb[128 * 64];
  __shared__ __align__(16) unsigned short Bsb[128 * 64];

  const int tid = threadIdx.x, w = tid >> 6, lane = tid & 63;
  const unsigned short* Az = (MODE == 0) ? Ab : Ab + (size_t)z * CAP_ * FOURC;
  const unsigned short* Bz = Bb + (size_t)z * ((MODE == 0) ? (size_t)FOURC * C_ : (size_t)C_ * FOURC);
  const float* biasz = bias + (size_t)e * ((MODE == 0) ? FOURC : C_);

  const int rsub = lane >> 3;        // 0..7
  const int kc   = lane & 7;         // 0..7 (16B chunk)
  const int sstore = (kc ^ rsub) * 8; // swizzled LDS chunk (element offset)

  // per-lane A source rows (gathered for MODE 0)
  int arow[4];
  #pragma unroll
  for (int i = 0; i < 4; i++) {
    const int m = m0 + w * 32 + i * 8 + rsub;
    if (MODE == 0) arow[i] = (m < Ne) ? slots[(size_t)e * CAP_ + m] : 0;
    else           arow[i] = m;   // always < CAP_
  }

  f32x4 acc[4][4];
  #pragma unroll
  for (int mi = 0; mi < 4; mi++)
    #pragma unroll
    for (int ni = 0; ni < 4; ni++) {
      f32x4 zz = {0.f, 0.f, 0.f, 0.f};
      acc[mi][ni] = zz;
    }

  const int wr = (w >> 1) * 64, wc = (w & 1) * 64;
  const int fr = lane & 15, fq = lane >> 4;
  const int nkt = Kd >> 6;

  for (int kt = 0; kt < nkt; kt++) {
    const int kb = kt * 64;
    // coalesced global loads (natural chunk kc -> 128B contiguous per 8 lanes)
    bf16x8 ga[4], gb[4];
    #pragma unroll
    for (int i = 0; i < 4; i++) {
      ga[i] = *(const bf16x8*)(Az + (size_t)arow[i] * lda + kb + kc * 8);
      gb[i] = *(const bf16x8*)(Bz + (size_t)(n0 + w * 32 + i * 8 + rsub) * ldb + kb + kc * 8);
    }
    __syncthreads();   // previous compute done with LDS
    #pragma unroll
    for (int i = 0; i < 4; i++) {
      const int rowL = w * 32 + i * 8 + rsub;
      *(bf16x8*)&Asb[rowL * 64 + sstore] = ga[i];
      *(bf16x8*)&Bsb[rowL * 64 + sstore] = gb[i];
    }
    __syncthreads();
    #pragma unroll
    for (int kk = 0; kk < 2; kk++) {
      const int kcl = kk * 4 + fq;
      bf16x8 af[4], bfr[4];
      #pragma unroll
      for (int t2 = 0; t2 < 4; t2++) {
        const int rowA = wr + t2 * 16 + fr;
        af[t2]  = *(const bf16x8*)&Asb[rowA * 64 + ((kcl ^ (rowA & 7)) << 3)];
        const int rowB = wc + t2 * 16 + fr;
        bfr[t2] = *(const bf16x8*)&Bsb[rowB * 64 + ((kcl ^ (rowB & 7)) << 3)];
      }
      #pragma unroll
      for (int mi = 0; mi < 4; mi++)
        #pragma unroll
        for (int ni = 0; ni < 4; ni++)
          acc[mi][ni] = __builtin_amdgcn_mfma_f32_16x16x32_bf16(af[mi], bfr[ni], acc[mi][ni], 0, 0, 0);
    }
  }

  // epilogue: D row=(lane>>4)*4+reg (m, from A), col=lane&15 (n, from B)
  #pragma unroll
  for (int mi = 0; mi < 4; mi++) {
    #pragma unroll
    for (int reg = 0; reg < 4; reg++) {
      const int m = m0 + wr + mi * 16 + fq * 4 + reg;
      if (MODE == 0) {
        #pragma unroll
        for (int ni = 0; ni < 4; ni++) {
          const int n = n0 + wc + ni * 16 + fr;
          const float r = fmaxf(acc[mi][ni][reg] + biasz[n], 0.f);
          h1out[(size_t)z * CAP_ * FOURC + (size_t)m * FOURC + n] = f2b(r * r);
        }
      } else {
        const int tok = (m < Ne) ? slots[(size_t)e * CAP_ + m] : -1;
        if (tok >= 0) {
          const float gg = gate[tok];
          #pragma unroll
          for (int ni = 0; ni < 4; ni++) {
            const int n = n0 + wc + ni * 16 + fr;
            fout[(size_t)tok * C_ + n] += (acc[mi][ni][reg] + biasz[n]) * gg;
          }
        }
      }
    }
  }
}

// ---------------- launcher ----------------
extern "C" void kernel_launch(void* const* d_in, const int* in_sizes, int n_in,
                              void* d_out, int out_size, void* d_ws, size_t ws_size,
                              hipStream_t stream) {
  const float* x        = (const float*)d_in[0];
  const float* x0       = (const float*)d_in[1];
  const float* noise    = (const float*)d_in[2];
  const float* lambdas  = (const float*)d_in[3];
  // d_in[4] = lamb: (1-lamb)*v + lamb*v == v -> unused
  const float* qkv_w    = (const float*)d_in[5];
  const float* c_proj_w = (const float*)d_in[6];
  const float* c_proj_b = (const float*)d_in[7];
  const float* router_w = (const float*)d_in[8];
  const float* router_b = (const float*)d_in[9];
  const float* noise_w  = (const float*)d_in[10];
  const float* noise_b  = (const float*)d_in[11];
  const float* ew1      = (const float*)d_in[12];
  const float* eb1      = (const float*)d_in[13];
  const float* ew2      = (const float*)d_in[14];
  const float* eb2      = (const float*)d_in[15];
  float* out = (float*)d_out;
  float* ws  = (float*)d_ws;

  float* xr  = ws + OFF_XR;
  float* h   = ws + OFF_H;
  int*   eid    = (int*)(ws + OFF_MISC);
  float* gate0  = ws + OFF_MISC + 4096;
  int*   slots  = (int*)(ws + OFF_MISC + 8192);
  int*   counts = (int*)(ws + OFF_MISC + 16384);
  float* a   = ws + OFF_A;
  float* ob  = ws + OFF_O;
  float* qb  = ws + OFF_Q;
  float* kb  = ws + OFF_K;
  float* vb  = ws + OFF_V;

  // 1) x' = l0*x + l1*x0 ; a = rmsnorm(x')
  k_norm<<<NTOK, 256, 0, stream>>>(x, x0, lambdas, xr, a);
  // 2) qkv = a @ qkv_w^T, scattered into head layout
  k_gemm<0><<<dim3(24, 32), 256, 0, stream>>>(a, qkv_w, nullptr, 1024, 1024, 1024,
      nullptr, nullptr, qb, kb, vb);
  // 3) per-head rmsnorm + rotary on q,k
  k_qkrot<<<dim3(16384, 2), 256, 0, stream>>>(qb, kb);
  // 4) causal attention
  k_attn<<<dim3(T_ / QBLK, B_ * H_), 512, 0, stream>>>(qb, kb, vb, ob);
  // 5) x2 = x' + o @ c_proj_w^T + b  -> d_out
  k_gemm<1><<<dim3(8, 32), 256, 0, stream>>>(ob, c_proj_w, out, 1024, 1024, 1024,
      c_proj_b, xr, nullptr, nullptr, nullptr);
  // 6) h = rmsnorm(x2)
  k_norm<<<NTOK, 256, 0, stream>>>(out, nullptr, nullptr, nullptr, h);
  // 7) router decisions
  k_router<<<NTOK, 256, 0, stream>>>(h, router_w, router_b, noise_w, noise_b,
                                     noise, eid, gate0);
  // 8) ordered compaction into per-expert slot lists
  k_assign<<<1, 256, 0, stream>>>(eid, slots, counts);

  // 9) expert FFNs in bf16 MFMA (chunked by workspace; ws >= 118MB proven -> chunk >= 3)
  float* exbase = ws + OFF_A;                       // attention scratch dead now
  unsigned short* h_b = (unsigned short*)exbase;    // 4096x1024 bf16 (2M floats)
  float* chunkbase = exbase + 2097152;
  const size_t ws_floats = ws_size / 4;
  long avail = (long)ws_floats - (long)(OFF_A + 2097152);
  int chunk = (int)(avail / (3L * 2097152));
  if (chunk < 1) chunk = 1;
  if (chunk > E_) chunk = E_;

  k_cast<<<2048, 256, 0, stream>>>(h, h_b, 1048576);

  for (int eb = 0; eb < E_; eb += chunk) {
    const int ce = (E_ - eb < chunk) ? (E_ - eb) : chunk;
    unsigned short* ew1b = (unsigned short*)chunkbase;
    unsigned short* ew2b = (unsigned short*)(chunkbase + (size_t)chunk * 2097152);
    unsigned short* h1b  = (unsigned short*)(chunkbase + (size_t)2 * chunk * 2097152);
    k_cast<<<2048, 256, 0, stream>>>(ew1 + (size_t)eb * 4194304, ew1b, ce * 1048576);
    k_cast<<<2048, 256, 0, stream>>>(ew2 + (size_t)eb * 4194304, ew2b, ce * 1048576);
    k_mgemm<0><<<dim3(32, 8, ce), 256, 0, stream>>>(h_b, ew1b, 1024, 1024, 1024,
        eb1, h1b, nullptr, slots, counts, nullptr, eb);
    k_mgemm<1><<<dim3(8, 8, ce), 256, 0, stream>>>(h1b, ew2b, 4096, 4096, 4096,
        eb2, nullptr, out, slots, counts, gate0, eb);
  }
}